// Round 12
// baseline (1919.756 us; speedup 1.0000x reference)
//
#include <hip/hip_runtime.h>
#include <math.h>

#define NB 8
#define NN 2048
#define ND 128
#define NITER 32

typedef unsigned short ushort_t;
typedef __attribute__((ext_vector_type(8))) short bf16x8;
typedef __attribute__((ext_vector_type(16))) float f32x16;

// eps = blur^2 = (5e-5)^2 = 2.5e-9. All potentials stored in LOG2-scaled units:
// F2 = (f/eps)*log2e etc. M2_ij = dot_ij/eps*log2e = q_ij * S_tile(row).
#define EPS_F   2.5e-9f
#define LNEG2   (-11.0f)                                   /* log2(1/2048) */
#define HSCALE2 ((float)(0.5 * 1.4426950408889634 / 2.5e-9))
#define SK2     ((float)(1.4426950408889634 / (255.0 * 2.5e-9)))

// ---------- preprocessing ----------

// wx[d] = sum_t x[0,t,d]^2  (reference quirk: batch 0 only), same for y
__global__ __launch_bounds__(256) void k_colsum(const float* __restrict__ x,
                                                const float* __restrict__ y,
                                                float* __restrict__ wx,
                                                float* __restrict__ wy) {
    const float* in = blockIdx.y ? y : x;
    float* w = blockIdx.y ? wy : wx;
    int d = blockIdx.x;
    int t = threadIdx.x;
    float sum = 0.f;
    for (int k = t; k < NN; k += 256) {
        float v = in[(size_t)k * ND + d];
        sum += v * v;
    }
    for (int off = 32; off > 0; off >>= 1) sum += __shfl_down(sum, off);
    __shared__ float ls[4];
    if ((t & 63) == 0) ls[t >> 6] = sum;
    __syncthreads();
    if (t == 0) w[d] = ls[0] + ls[1] + ls[2] + ls[3];
}

// v2 = x^2/wx split into bf16 hi + bf16 lo residual; h2 = 0.5*|v2 row|^2/eps*log2e
__global__ __launch_bounds__(128) void k_norm(const float* __restrict__ x,
                                              const float* __restrict__ y,
                                              const float* __restrict__ wx,
                                              const float* __restrict__ wy,
                                              ushort_t* __restrict__ X2h,
                                              ushort_t* __restrict__ X2l,
                                              ushort_t* __restrict__ Y2h,
                                              ushort_t* __restrict__ Y2l,
                                              float* __restrict__ hx,
                                              float* __restrict__ hy) {
    int gx = blockIdx.x;                 // b*NN + i
    const float* in = blockIdx.y ? y : x;
    const float* w  = blockIdx.y ? wy : wx;
    ushort_t* oh = blockIdx.y ? Y2h : X2h;
    ushort_t* ol = blockIdx.y ? Y2l : X2l;
    float* h  = blockIdx.y ? hy : hx;
    int d = threadIdx.x;
    size_t base = (size_t)gx * ND;
    float v = in[base + d];
    float v2 = (v * v) / w[d];
    // RTNE bf16 split: v2 = hi + lo + O(2^-17 * v2)
    unsigned u = __float_as_uint(v2);
    unsigned short hs = (unsigned short)((u + 0x7fffu + ((u >> 16) & 1u)) >> 16);
    float hf = __uint_as_float((unsigned)hs << 16);
    float lo = v2 - hf;
    unsigned ul = __float_as_uint(lo);
    unsigned short lsq = (unsigned short)((ul + 0x7fffu + ((ul >> 16) & 1u)) >> 16);
    oh[base + d] = hs;
    ol[base + d] = lsq;
    float sq = v2 * v2;
    for (int off = 32; off > 0; off >>= 1) sq += __shfl_down(sq, off);
    __shared__ float ls[2];
    if ((d & 63) == 0) ls[d >> 6] = sq;
    __syncthreads();
    if (d == 0) h[gx] = (ls[0] + ls[1]) * HSCALE2;
}

__global__ __launch_bounds__(256) void k_init(const float* __restrict__ hx,
                                              const float* __restrict__ hy,
                                              float* __restrict__ Gt,
                                              float* __restrict__ Px, float* __restrict__ Pax,
                                              float* __restrict__ Py, float* __restrict__ Pay) {
    int tid = blockIdx.x * 256 + threadIdx.x;
    Gt[tid]  = LNEG2 - hy[tid];
    Px[tid]  = 0.f;
    Py[tid]  = 0.f;
    Pax[tid] = LNEG2 - hx[tid];
    Pay[tid] = LNEG2 - hy[tid];
}

// ---------- MFMA GEMM (bf16 hi/lo split) + per-(row,128-col-tile) max u8 quant ----------
// dot = hi*hi + hi*lo + lo*hi  (lo*lo dropped: ~2^-18 relative).
// C/D layout (m74/m101): col=lane&31, row=(reg&3)+8*(reg>>2)+4*(lane>>5).
// TRI variant: symmetric input (xx/yy) -> lower-triangle grid, mirror via DO_T.
template<bool DO_T, bool TRI>
__global__ __launch_bounds__(256, 4) void k_gemm(const ushort_t* __restrict__ Ah,
                                                 const ushort_t* __restrict__ Al,
                                                 const ushort_t* __restrict__ Bh,
                                                 const ushort_t* __restrict__ Bl,
                                                 float* __restrict__ Srow,
                                                 float* __restrict__ Scol,
                                                 unsigned char* __restrict__ C,
                                                 unsigned char* __restrict__ Ct,
                                                 int b0) {
    __shared__ __align__(16) char smem[24576];
    int bi, bj, bz;
    if (TRI) {
        int uu = blockIdx.x;
        bi = (int)((sqrtf(8.f * uu + 1.f) - 1.f) * 0.5f);
        bj = uu - bi * (bi + 1) / 2;           // bj <= bi
        bz = blockIdx.y;
    } else {
        bi = blockIdx.x; bj = blockIdx.y; bz = blockIdx.z;
    }
    size_t bg = (size_t)(b0 + bz);
    int t = threadIdx.x;
    int w = t >> 6, l = t & 63;
    int lr = l & 31, hi5 = l >> 5;
    int lk = hi5 * 16;                          // frag k-offset bytes

    f32x16 acc[4];
#pragma unroll
    for (int ct = 0; ct < 4; ++ct)
#pragma unroll
        for (int i = 0; i < 16; ++i) acc[ct][i] = 0.f;

    const int srow = t >> 1;
    const int spart = (t & 1) << 4;             // 0/16 bytes
    const size_t arow0 = (bg * NN + (size_t)bi * 128 + srow) * ND;
    const size_t brow0 = (bg * NN + (size_t)bj * 128 + srow) * ND;

    for (int kt = 0; kt < 8; ++kt) {
        __syncthreads();
        {
            size_t gA = (arow0 + kt * 16 + (t & 1) * 8) * 2;
            size_t gB = (brow0 + kt * 16 + (t & 1) * 8) * 2;
            int ld = srow * 48 + spart;
            *(uint4*)(smem + ld)         = *(const uint4*)((const char*)Ah + gA);
            *(uint4*)(smem + 6144 + ld)  = *(const uint4*)((const char*)Al + gA);
            *(uint4*)(smem + 12288 + ld) = *(const uint4*)((const char*)Bh + gB);
            *(uint4*)(smem + 18432 + ld) = *(const uint4*)((const char*)Bl + gB);
        }
        __syncthreads();
        int ar = (32 * w + lr) * 48 + lk;
        bf16x8 ah = *(const bf16x8*)(smem + ar);
        bf16x8 al = *(const bf16x8*)(smem + 6144 + ar);
#pragma unroll
        for (int ct = 0; ct < 4; ++ct) {
            int br = (32 * ct + lr) * 48 + lk;
            bf16x8 bh = *(const bf16x8*)(smem + 12288 + br);
            bf16x8 bl = *(const bf16x8*)(smem + 18432 + br);
            acc[ct] = __builtin_amdgcn_mfma_f32_32x32x16_bf16(ah, bh, acc[ct], 0, 0, 0);
            acc[ct] = __builtin_amdgcn_mfma_f32_32x32x16_bf16(ah, bl, acc[ct], 0, 0, 0);
            acc[ct] = __builtin_amdgcn_mfma_f32_32x32x16_bf16(al, bh, acc[ct], 0, 0, 0);
        }
    }

    // ---- row maxes (over the block's 128 cols) + scales ----
    float inv_r[16];
#pragma unroll
    for (int r = 0; r < 16; ++r) {
        float m0 = fmaxf(fmaxf(acc[0][r], acc[1][r]), fmaxf(acc[2][r], acc[3][r]));
#pragma unroll
        for (int off = 1; off <= 16; off <<= 1) m0 = fmaxf(m0, __shfl_xor(m0, off));
        m0 = fmaxf(m0, 1e-30f);
        inv_r[r] = 255.f / m0;
        if (lr == 0) {
            int rowblk = (r & 3) + 8 * (r >> 2) + 4 * hi5 + 32 * w;
            Srow[(bg * NN + (size_t)bi * 128 + rowblk) * 16 + bj] = m0 * SK2;
        }
    }
    __syncthreads();            // staging dead; T aliases smem
    unsigned char (*T)[144] = (unsigned char (*)[144])smem;
#pragma unroll
    for (int ct = 0; ct < 4; ++ct)
#pragma unroll
        for (int r = 0; r < 16; ++r) {
            int rowblk = (r & 3) + 8 * (r >> 2) + 4 * hi5 + 32 * w;
            int q = (int)fmaf(acc[ct][r], inv_r[r], 0.5f);
            T[rowblk][ct * 32 + lr] = (unsigned char)(q > 255 ? 255 : q);
        }
    __syncthreads();
    {
        int r2 = t >> 1, hf = t & 1;
        size_t grow = (size_t)bz * NN + (size_t)bi * 128 + r2;
        unsigned char* dst = C + grow * NN + (size_t)bj * 128 + 64 * hf;
        const uint4* src = (const uint4*)&T[r2][64 * hf];
        uint4 v0 = src[0], v1 = src[1], v2 = src[2], v3 = src[3];
        *(uint4*)(dst + 0)  = v0;
        *(uint4*)(dst + 16) = v1;
        *(uint4*)(dst + 32) = v2;
        *(uint4*)(dst + 48) = v3;
    }
    if (DO_T) {
        float* sinv = (float*)(smem + 18432);
        float* CMf  = (float*)(smem + 18944);   // [4][128]
        __syncthreads();                        // pass-1 T reads done
#pragma unroll
        for (int ct = 0; ct < 4; ++ct) {
            float cm = acc[ct][0];
#pragma unroll
            for (int r = 1; r < 16; ++r) cm = fmaxf(cm, acc[ct][r]);
            cm = fmaxf(cm, __shfl_xor(cm, 32));
            if (hi5 == 0) CMf[w * 128 + ct * 32 + lr] = cm;
        }
        __syncthreads();
        if (t < 128) {
            float cm = fmaxf(fmaxf(CMf[t], CMf[128 + t]), fmaxf(CMf[256 + t], CMf[384 + t]));
            cm = fmaxf(cm, 1e-30f);
            Scol[(bg * NN + (size_t)bj * 128 + t) * 16 + bi] = cm * SK2;
            sinv[t] = 255.f / cm;
        }
        __syncthreads();
#pragma unroll
        for (int ct = 0; ct < 4; ++ct) {
            float iv = sinv[ct * 32 + lr];
#pragma unroll
            for (int r = 0; r < 16; ++r) {
                int rowblk = (r & 3) + 8 * (r >> 2) + 4 * hi5 + 32 * w;
                int q = (int)fmaf(acc[ct][r], iv, 0.5f);
                T[ct * 32 + lr][rowblk] = (unsigned char)(q > 255 ? 255 : q);
            }
        }
        __syncthreads();
        {
            int r2 = t >> 1, hf = t & 1;
            size_t grow = (size_t)bz * NN + (size_t)bj * 128 + r2;
            unsigned char* dst = Ct + grow * NN + (size_t)bi * 128 + 64 * hf;
            const uint4* src = (const uint4*)&T[r2][64 * hf];
            uint4 v0 = src[0], v1 = src[1], v2 = src[2], v3 = src[3];
            *(uint4*)(dst + 0)  = v0;
            *(uint4*)(dst + 16) = v1;
            *(uint4*)(dst + 32) = v2;
            *(uint4*)(dst + 48) = v3;
        }
    }
}

// ---------- Sinkhorn iteration phase ----------
// One launch per phase (launch boundary = grid barrier; r8: grid.sync ~60us).
// TILE-SKIP: only terms within 64 log2-units of the row max contribute to the
// f32 lse sum (max term = 1; anything below adds < 2^-53 relative). Per row:
// bound each 128-col tile by 255*sc_tile + vtmax_tile; read the best-bound
// tile to get a true max m^; lanes with bound < m^ - 64 skip their loads
// entirely (true-max lane always survives: bound >= val >= mx >= m^).
struct SArgs {
    const unsigned char *Qxy, *Qyx, *Qxx, *Qyy;   // group-relative [G][2048][2048]
    const float *Sxy, *Syx, *Sxx, *Syy;           // global [NB*NN*16]
    float *Fa, *Gt, *Px, *Py;                     // global [NB*NN]
    float *PaxA, *PaxB, *PayA, *PayB;             // global [NB*NN]
    const float *hx, *hy;                         // global [NB*NN]
    int b0;                                       // batch base of this group
};

#define BSHIFT 7

#define SRM(W, U) \
    m0 = fmaxf(m0, fmaf((float)((W) & 0xffu),         sc, vv[4*(U)+0])); \
    m1 = fmaxf(m1, fmaf((float)(((W) >> 8) & 0xffu),  sc, vv[4*(U)+1])); \
    m2 = fmaxf(m2, fmaf((float)(((W) >> 16) & 0xffu), sc, vv[4*(U)+2])); \
    m3 = fmaxf(m3, fmaf((float)((W) >> 24),           sc, vv[4*(U)+3]));

#define SRS(W, U) \
    s0 += __builtin_amdgcn_exp2f(fmaf((float)((W) & 0xffu),         sc, vv[4*(U)+0]) - mx); \
    s1 += __builtin_amdgcn_exp2f(fmaf((float)(((W) >> 8) & 0xffu),  sc, vv[4*(U)+1]) - mx); \
    s2 += __builtin_amdgcn_exp2f(fmaf((float)(((W) >> 16) & 0xffu), sc, vv[4*(U)+2]) - mx); \
    s3 += __builtin_amdgcn_exp2f(fmaf((float)((W) >> 24),           sc, vv[4*(U)+3]) - mx);

#define QMAX32(OUT) { \
    float m0 = -INFINITY, m1 = -INFINITY, m2 = -INFINITY, m3 = -INFINITY; \
    SRM(qa.x,0) SRM(qa.y,1) SRM(qa.z,2) SRM(qa.w,3) \
    SRM(qb.x,4) SRM(qb.y,5) SRM(qb.z,6) SRM(qb.w,7) \
    OUT = fmaxf(fmaxf(m0, m1), fmaxf(m2, m3)); }

#define WMAXF(V) \
    V = fmaxf(V, __shfl_xor(V, 32)); V = fmaxf(V, __shfl_xor(V, 16)); \
    V = fmaxf(V, __shfl_xor(V, 8));  V = fmaxf(V, __shfl_xor(V, 4)); \
    V = fmaxf(V, __shfl_xor(V, 2));  V = fmaxf(V, __shfl_xor(V, 1));

__global__ __launch_bounds__(256, 4) void k_step(SArgs a, int cur, int ph) {
    __shared__ __align__(16) float vs[2048];
    __shared__ float vtm[16];
    int nblk = gridDim.x;
    int bid = blockIdx.x;
    int half = nblk >> 1;
    int mh = bid >= half;
    int rem = mh ? bid - half : bid;
    int brel = rem >> BSHIFT;
    int rb = rem & ((1 << BSHIFT) - 1);
    const int rpb = NN >> BSHIFT;      // 16 rows per block
    const int rpw = rpb >> 2;          // 4 rows per wave
    int r0 = rb * rpb;
    int t = threadIdx.x;
    int w = t >> 6, l = t & 63;
    size_t bg = (size_t)(a.b0 + brel);
    size_t gx0 = (bg << 11) + r0 + w * rpw;                       // global row base (this wave)
    size_t qbase = ((((size_t)brel << 11) + r0 + w * rpw) << 11); // group-relative Q offset

    const unsigned char* Q;
    const float* S;
    const float* v;
    float* Pa_w = nullptr;
    const float* hp = nullptr;
    float* Pp = nullptr;
    if (ph == 0) {
        if (mh == 0) { Q = a.Qxy; S = a.Sxy; v = a.Gt + (bg << 11); }
        else { Q = a.Qxx; S = a.Sxx; v = (cur ? a.PaxB : a.PaxA) + (bg << 11);
               Pa_w = cur ? a.PaxA : a.PaxB; hp = a.hx; Pp = a.Px; }
    } else {
        if (mh == 0) { Q = a.Qyx; S = a.Syx; v = a.Fa + (bg << 11); }
        else { Q = a.Qyy; S = a.Syy; v = (cur ? a.PayB : a.PayA) + (bg << 11);
               Pa_w = cur ? a.PayA : a.PayB; hp = a.hy; Pp = a.Py; }
    }
    float* out0 = (ph == 0) ? a.Fa : a.Gt;

    // stage v into LDS (XOR swizzle) + per-128-col-tile max of v
    {
        const float4* gv = (const float4*)v;
        float4 a0 = gv[2 * t], a1 = gv[2 * t + 1];
        int B0 = t << 5;
        int sw = ((t >> 2) & 7) << 4;
        *(float4*)((char*)vs + (B0 ^ sw)) = a0;
        *(float4*)((char*)vs + ((B0 + 16) ^ sw)) = a1;
        float m8 = fmaxf(fmaxf(fmaxf(a0.x, a0.y), fmaxf(a0.z, a0.w)),
                         fmaxf(fmaxf(a1.x, a1.y), fmaxf(a1.z, a1.w)));
        m8 = fmaxf(m8, __shfl_xor(m8, 1));
        m8 = fmaxf(m8, __shfl_xor(m8, 2));
        m8 = fmaxf(m8, __shfl_xor(m8, 4));
        m8 = fmaxf(m8, __shfl_xor(m8, 8));
        if ((t & 15) == 0) vtm[t >> 4] = m8;    // 16 threads/tile, same wave
    }
    __syncthreads();
    float vv[32];
#pragma unroll
    for (int u = 0; u < 8; ++u) {
        int B = ((l << 7) + (u << 4)) ^ ((l & 7) << 4);
        *(float4*)&vv[u * 4] = *(const float4*)((char*)vs + B);
    }
    float vt = vtm[l >> 2];

    const unsigned char* rp0 = Q + qbase + ((size_t)l << 5);
    const float* Sp = S + (gx0 << 4) + (l >> 2);
    float scr0 = Sp[0], scr1 = Sp[16], scr2 = Sp[32], scr3 = Sp[48];

#pragma unroll
    for (int r = 0; r < 4; ++r) {
        float sc = (r == 0) ? scr0 : (r == 1) ? scr1 : (r == 2) ? scr2 : scr3;
        float bound = fmaf(255.f, sc, vt);
        float mxb = bound;
        WMAXF(mxb)
        unsigned long long msk = __ballot(bound == mxb);
        int tbest = (__ffsll(msk) - 1) >> 2;
        bool inbest = (l >> 2) == tbest;
        uint4 qa, qb;
        float lmax = -INFINITY;
        if (inbest) {
            const unsigned char* p = rp0 + ((size_t)r << 11);
            qa = *(const uint4*)p; qb = *(const uint4*)(p + 16);
            QMAX32(lmax)
        }
        float mhat = lmax;
        WMAXF(mhat)
        bool alive = bound >= mhat - 64.f;
        if (alive && !inbest) {
            const unsigned char* p = rp0 + ((size_t)r << 11);
            qa = *(const uint4*)p; qb = *(const uint4*)(p + 16);
            QMAX32(lmax)
        }
        float mx = lmax;
        WMAXF(mx)
        float ss = 0.f;
        if (alive) {
            float s0 = 0.f, s1 = 0.f, s2 = 0.f, s3 = 0.f;
            SRS(qa.x,0) SRS(qa.y,1) SRS(qa.z,2) SRS(qa.w,3)
            SRS(qb.x,4) SRS(qb.y,5) SRS(qb.z,6) SRS(qb.w,7)
            ss = (s0 + s1) + (s2 + s3);
        }
        ss += __shfl_xor(ss, 32); ss += __shfl_xor(ss, 16); ss += __shfl_xor(ss, 8);
        ss += __shfl_xor(ss, 4);  ss += __shfl_xor(ss, 2);  ss += __shfl_xor(ss, 1);
        if (l == 0) {
            size_t gx = gx0 + r;
            float lse2 = mx + log2f(ss);
            if (mh == 0) {
                out0[gx] = LNEG2 - lse2;
            } else {
                float pn = 0.5f * (Pp[gx] + hp[gx] - lse2);
                Pp[gx] = pn;
                Pa_w[gx] = LNEG2 + pn - hp[gx];
            }
        }
    }
}

// ---------- final reduction (log2 domain -> natural) ----------
__global__ __launch_bounds__(256) void k_final(const float* __restrict__ Fa, const float* __restrict__ Gt,
                                               const float* __restrict__ Px, const float* __restrict__ Py,
                                               const float* __restrict__ hx, const float* __restrict__ hy,
                                               float* __restrict__ out) {
    int t = threadIdx.x;
    double acc = 0.0;
    for (int i = t; i < NB * NN; i += 256) {
        acc += (double)(Fa[i] + hx[i]) + (double)(Gt[i] + hy[i])
             - (double)Px[i] - (double)Py[i];
    }
    __shared__ double ld[256];
    ld[t] = acc;
    __syncthreads();
    for (int off = 128; off > 0; off >>= 1) {
        if (t < off) ld[t] += ld[t + off];
        __syncthreads();
    }
    if (t == 0) {
        double total = ld[0] - 2.0 * (double)LNEG2 * (double)(NB * NN);
        out[0] = (float)((double)EPS_F * 0.6931471805599453 * total / (double)NN);
    }
}

extern "C" void kernel_launch(void* const* d_in, const int* in_sizes, int n_in,
                              void* d_out, int out_size, void* d_ws, size_t ws_size,
                              hipStream_t stream) {
    (void)in_sizes; (void)n_in; (void)out_size;
    const float* x = (const float*)d_in[0];
    const float* y = (const float*)d_in[1];
    float* out = (float*)d_out;

    char* ws = (char*)d_ws;
    size_t off = 0;
    auto alloc = [&](size_t bytes) -> char* {
        char* p = ws + off;
        off += (bytes + 255) & ~(size_t)255;
        return p;
    };

    ushort_t* X2h = (ushort_t*)alloc((size_t)NB * NN * ND * 2);
    ushort_t* X2l = (ushort_t*)alloc((size_t)NB * NN * ND * 2);
    ushort_t* Y2h = (ushort_t*)alloc((size_t)NB * NN * ND * 2);
    ushort_t* Y2l = (ushort_t*)alloc((size_t)NB * NN * ND * 2);
    float* wx = (float*)alloc(ND * 4);
    float* wy = (float*)alloc(ND * 4);
    float* hx = (float*)alloc((size_t)NB * NN * 4);
    float* hy = (float*)alloc((size_t)NB * NN * 4);
    float* Fa = (float*)alloc((size_t)NB * NN * 4);
    float* Gt = (float*)alloc((size_t)NB * NN * 4);
    float* Px = (float*)alloc((size_t)NB * NN * 4);
    float* Py = (float*)alloc((size_t)NB * NN * 4);
    float* PaxA = (float*)alloc((size_t)NB * NN * 4);
    float* PaxB = (float*)alloc((size_t)NB * NN * 4);
    float* PayA = (float*)alloc((size_t)NB * NN * 4);
    float* PayB = (float*)alloc((size_t)NB * NN * 4);
    float* Sxy = (float*)alloc((size_t)NB * NN * 16 * 4);
    float* Syx = (float*)alloc((size_t)NB * NN * 16 * 4);
    float* Sxx = (float*)alloc((size_t)NB * NN * 16 * 4);
    float* Syy = (float*)alloc((size_t)NB * NN * 16 * 4);

    // Q matrices: 4 * 4MB per batch in group; shrink group if workspace is small
    size_t small_end = off;
    size_t matBytes = (size_t)NN * NN;               // 4 MB (u8)
    int G = NB;
    while (G > 1 && small_end + 4 * matBytes * (size_t)G + 4096 > ws_size) G >>= 1;
    unsigned char* Qxy = (unsigned char*)alloc(matBytes * (size_t)G);
    unsigned char* Qyx = (unsigned char*)alloc(matBytes * (size_t)G);
    unsigned char* Qxx = (unsigned char*)alloc(matBytes * (size_t)G);
    unsigned char* Qyy = (unsigned char*)alloc(matBytes * (size_t)G);

    int nblk = 2 * G << BSHIFT;                      // 2048 blocks at G=8

    k_colsum<<<dim3(ND, 2), 256, 0, stream>>>(x, y, wx, wy);
    k_norm<<<dim3(NB * NN, 2), 128, 0, stream>>>(x, y, wx, wy, X2h, X2l, Y2h, Y2l, hx, hy);
    k_init<<<dim3(NB * NN / 256), 256, 0, stream>>>(hx, hy, Gt, Px, PaxA, Py, PayA);

    for (int b0 = 0; b0 < NB; b0 += G) {
        // xy: full grid, emits Qxy (row-scaled) + Qyx (transposed, col-scaled)
        k_gemm<true, false><<<dim3(16, 16, G), 256, 0, stream>>>(
            X2h, X2l, Y2h, Y2l, Sxy, Syx, Qxy, Qyx, b0);
        // xx/yy: symmetric -> lower-triangle grid; DO_T mirrors into upper half
        k_gemm<true, true><<<dim3(136, G), 256, 0, stream>>>(
            X2h, X2l, X2h, X2l, Sxx, Sxx, Qxx, Qxx, b0);
        k_gemm<true, true><<<dim3(136, G), 256, 0, stream>>>(
            Y2h, Y2l, Y2h, Y2l, Syy, Syy, Qyy, Qyy, b0);

        SArgs sa;
        sa.Qxy = Qxy; sa.Qyx = Qyx; sa.Qxx = Qxx; sa.Qyy = Qyy;
        sa.Sxy = Sxy; sa.Syx = Syx; sa.Sxx = Sxx; sa.Syy = Syy;
        sa.Fa = Fa; sa.Gt = Gt; sa.Px = Px; sa.Py = Py;
        sa.PaxA = PaxA; sa.PaxB = PaxB; sa.PayA = PayA; sa.PayB = PayB;
        sa.hx = hx; sa.hy = hy; sa.b0 = b0;

        int cur = 0;
        for (int it = 0; it < NITER; ++it) {
            k_step<<<dim3(nblk), 256, 0, stream>>>(sa, cur, 0);
            k_step<<<dim3(nblk), 256, 0, stream>>>(sa, cur, 1);
            cur ^= 1;
        }
    }
    k_final<<<dim3(1), 256, 0, stream>>>(Fa, Gt, Px, Py, hx, hy, out);
}

// Round 13
// 1083.898 us; speedup vs baseline: 1.7712x; 1.7712x over previous
//
#include <hip/hip_runtime.h>
#include <math.h>

#define NB 8
#define NN 2048
#define ND 128
#define NITER 32
// Sym (debiasing) potentials converge bit-exactly in f32 within ~2 iterations:
// cost diag C_ii=0, off-diag C/eps ~ 1e4 log2-units -> lse = its diagonal term
// -> p fixed at -loga/2 from iter 2 on. Run 12 for 6x margin, then stop.
#define SYMITER 12

typedef unsigned short ushort_t;
typedef __attribute__((ext_vector_type(8))) short bf16x8;
typedef __attribute__((ext_vector_type(16))) float f32x16;

// eps = blur^2 = (5e-5)^2 = 2.5e-9. All potentials stored in LOG2-scaled units:
// F2 = (f/eps)*log2e etc. M2_ij = dot_ij/eps*log2e = q_ij * S_tile(row).
#define EPS_F   2.5e-9f
#define LNEG2   (-11.0f)                                   /* log2(1/2048) */
#define HSCALE2 ((float)(0.5 * 1.4426950408889634 / 2.5e-9))
#define SK2     ((float)(1.4426950408889634 / (255.0 * 2.5e-9)))

// ---------- preprocessing ----------

// wx[d] = sum_t x[0,t,d]^2  (reference quirk: batch 0 only), same for y
__global__ __launch_bounds__(256) void k_colsum(const float* __restrict__ x,
                                                const float* __restrict__ y,
                                                float* __restrict__ wx,
                                                float* __restrict__ wy) {
    const float* in = blockIdx.y ? y : x;
    float* w = blockIdx.y ? wy : wx;
    int d = blockIdx.x;
    int t = threadIdx.x;
    float sum = 0.f;
    for (int k = t; k < NN; k += 256) {
        float v = in[(size_t)k * ND + d];
        sum += v * v;
    }
    for (int off = 32; off > 0; off >>= 1) sum += __shfl_down(sum, off);
    __shared__ float ls[4];
    if ((t & 63) == 0) ls[t >> 6] = sum;
    __syncthreads();
    if (t == 0) w[d] = ls[0] + ls[1] + ls[2] + ls[3];
}

// v2 = x^2/wx split into bf16 hi + bf16 lo residual; h2 = 0.5*|v2 row|^2/eps*log2e
__global__ __launch_bounds__(128) void k_norm(const float* __restrict__ x,
                                              const float* __restrict__ y,
                                              const float* __restrict__ wx,
                                              const float* __restrict__ wy,
                                              ushort_t* __restrict__ X2h,
                                              ushort_t* __restrict__ X2l,
                                              ushort_t* __restrict__ Y2h,
                                              ushort_t* __restrict__ Y2l,
                                              float* __restrict__ hx,
                                              float* __restrict__ hy) {
    int gx = blockIdx.x;                 // b*NN + i
    const float* in = blockIdx.y ? y : x;
    const float* w  = blockIdx.y ? wy : wx;
    ushort_t* oh = blockIdx.y ? Y2h : X2h;
    ushort_t* ol = blockIdx.y ? Y2l : X2l;
    float* h  = blockIdx.y ? hy : hx;
    int d = threadIdx.x;
    size_t base = (size_t)gx * ND;
    float v = in[base + d];
    float v2 = (v * v) / w[d];
    // RTNE bf16 split: v2 = hi + lo + O(2^-17 * v2)
    unsigned u = __float_as_uint(v2);
    unsigned short hs = (unsigned short)((u + 0x7fffu + ((u >> 16) & 1u)) >> 16);
    float hf = __uint_as_float((unsigned)hs << 16);
    float lo = v2 - hf;
    unsigned ul = __float_as_uint(lo);
    unsigned short lsq = (unsigned short)((ul + 0x7fffu + ((ul >> 16) & 1u)) >> 16);
    oh[base + d] = hs;
    ol[base + d] = lsq;
    float sq = v2 * v2;
    for (int off = 32; off > 0; off >>= 1) sq += __shfl_down(sq, off);
    __shared__ float ls[2];
    if ((d & 63) == 0) ls[d >> 6] = sq;
    __syncthreads();
    if (d == 0) h[gx] = (ls[0] + ls[1]) * HSCALE2;
}

__global__ __launch_bounds__(256) void k_init(const float* __restrict__ hx,
                                              const float* __restrict__ hy,
                                              float* __restrict__ Gt,
                                              float* __restrict__ Px, float* __restrict__ Pax,
                                              float* __restrict__ Py, float* __restrict__ Pay) {
    int tid = blockIdx.x * 256 + threadIdx.x;
    Gt[tid]  = LNEG2 - hy[tid];
    Px[tid]  = 0.f;
    Py[tid]  = 0.f;
    Pax[tid] = LNEG2 - hx[tid];
    Pay[tid] = LNEG2 - hy[tid];
}

// ---------- MFMA GEMM (bf16 hi/lo split) + per-(row,128-col-tile) max u8 quant ----------
// dot = hi*hi + hi*lo + lo*hi  (lo*lo dropped: ~2^-18 relative).
// C/D layout (m74/m101): col=lane&31, row=(reg&3)+8*(reg>>2)+4*(lane>>5).
// TRI variant: symmetric input (xx/yy) -> lower-triangle grid, mirror via DO_T.
template<bool DO_T, bool TRI>
__global__ __launch_bounds__(256, 4) void k_gemm(const ushort_t* __restrict__ Ah,
                                                 const ushort_t* __restrict__ Al,
                                                 const ushort_t* __restrict__ Bh,
                                                 const ushort_t* __restrict__ Bl,
                                                 float* __restrict__ Srow,
                                                 float* __restrict__ Scol,
                                                 unsigned char* __restrict__ C,
                                                 unsigned char* __restrict__ Ct,
                                                 int b0) {
    __shared__ __align__(16) char smem[24576];
    int bi, bj, bz;
    if (TRI) {
        int uu = blockIdx.x;
        bi = (int)((sqrtf(8.f * uu + 1.f) - 1.f) * 0.5f);
        bj = uu - bi * (bi + 1) / 2;           // bj <= bi
        bz = blockIdx.y;
    } else {
        bi = blockIdx.x; bj = blockIdx.y; bz = blockIdx.z;
    }
    size_t bg = (size_t)(b0 + bz);
    int t = threadIdx.x;
    int w = t >> 6, l = t & 63;
    int lr = l & 31, hi5 = l >> 5;
    int lk = hi5 * 16;                          // frag k-offset bytes

    f32x16 acc[4];
#pragma unroll
    for (int ct = 0; ct < 4; ++ct)
#pragma unroll
        for (int i = 0; i < 16; ++i) acc[ct][i] = 0.f;

    const int srow = t >> 1;
    const int spart = (t & 1) << 4;             // 0/16 bytes
    const size_t arow0 = (bg * NN + (size_t)bi * 128 + srow) * ND;
    const size_t brow0 = (bg * NN + (size_t)bj * 128 + srow) * ND;

    for (int kt = 0; kt < 8; ++kt) {
        __syncthreads();
        {
            size_t gA = (arow0 + kt * 16 + (t & 1) * 8) * 2;
            size_t gB = (brow0 + kt * 16 + (t & 1) * 8) * 2;
            int ld = srow * 48 + spart;
            *(uint4*)(smem + ld)         = *(const uint4*)((const char*)Ah + gA);
            *(uint4*)(smem + 6144 + ld)  = *(const uint4*)((const char*)Al + gA);
            *(uint4*)(smem + 12288 + ld) = *(const uint4*)((const char*)Bh + gB);
            *(uint4*)(smem + 18432 + ld) = *(const uint4*)((const char*)Bl + gB);
        }
        __syncthreads();
        int ar = (32 * w + lr) * 48 + lk;
        bf16x8 ah = *(const bf16x8*)(smem + ar);
        bf16x8 al = *(const bf16x8*)(smem + 6144 + ar);
#pragma unroll
        for (int ct = 0; ct < 4; ++ct) {
            int br = (32 * ct + lr) * 48 + lk;
            bf16x8 bh = *(const bf16x8*)(smem + 12288 + br);
            bf16x8 bl = *(const bf16x8*)(smem + 18432 + br);
            acc[ct] = __builtin_amdgcn_mfma_f32_32x32x16_bf16(ah, bh, acc[ct], 0, 0, 0);
            acc[ct] = __builtin_amdgcn_mfma_f32_32x32x16_bf16(ah, bl, acc[ct], 0, 0, 0);
            acc[ct] = __builtin_amdgcn_mfma_f32_32x32x16_bf16(al, bh, acc[ct], 0, 0, 0);
        }
    }

    // ---- row maxes (over the block's 128 cols) + scales ----
    float inv_r[16];
#pragma unroll
    for (int r = 0; r < 16; ++r) {
        float m0 = fmaxf(fmaxf(acc[0][r], acc[1][r]), fmaxf(acc[2][r], acc[3][r]));
#pragma unroll
        for (int off = 1; off <= 16; off <<= 1) m0 = fmaxf(m0, __shfl_xor(m0, off));
        m0 = fmaxf(m0, 1e-30f);
        inv_r[r] = 255.f / m0;
        if (lr == 0) {
            int rowblk = (r & 3) + 8 * (r >> 2) + 4 * hi5 + 32 * w;
            Srow[(bg * NN + (size_t)bi * 128 + rowblk) * 16 + bj] = m0 * SK2;
        }
    }
    __syncthreads();            // staging dead; T aliases smem
    unsigned char (*T)[144] = (unsigned char (*)[144])smem;
#pragma unroll
    for (int ct = 0; ct < 4; ++ct)
#pragma unroll
        for (int r = 0; r < 16; ++r) {
            int rowblk = (r & 3) + 8 * (r >> 2) + 4 * hi5 + 32 * w;
            int q = (int)fmaf(acc[ct][r], inv_r[r], 0.5f);
            T[rowblk][ct * 32 + lr] = (unsigned char)(q > 255 ? 255 : q);
        }
    __syncthreads();
    {
        int r2 = t >> 1, hf = t & 1;
        size_t grow = (size_t)bz * NN + (size_t)bi * 128 + r2;
        unsigned char* dst = C + grow * NN + (size_t)bj * 128 + 64 * hf;
        const uint4* src = (const uint4*)&T[r2][64 * hf];
        uint4 v0 = src[0], v1 = src[1], v2 = src[2], v3 = src[3];
        *(uint4*)(dst + 0)  = v0;
        *(uint4*)(dst + 16) = v1;
        *(uint4*)(dst + 32) = v2;
        *(uint4*)(dst + 48) = v3;
    }
    if (DO_T) {
        float* sinv = (float*)(smem + 18432);
        float* CMf  = (float*)(smem + 18944);   // [4][128]
        __syncthreads();                        // pass-1 T reads done
#pragma unroll
        for (int ct = 0; ct < 4; ++ct) {
            float cm = acc[ct][0];
#pragma unroll
            for (int r = 1; r < 16; ++r) cm = fmaxf(cm, acc[ct][r]);
            cm = fmaxf(cm, __shfl_xor(cm, 32));
            if (hi5 == 0) CMf[w * 128 + ct * 32 + lr] = cm;
        }
        __syncthreads();
        if (t < 128) {
            float cm = fmaxf(fmaxf(CMf[t], CMf[128 + t]), fmaxf(CMf[256 + t], CMf[384 + t]));
            cm = fmaxf(cm, 1e-30f);
            Scol[(bg * NN + (size_t)bj * 128 + t) * 16 + bi] = cm * SK2;
            sinv[t] = 255.f / cm;
        }
        __syncthreads();
#pragma unroll
        for (int ct = 0; ct < 4; ++ct) {
            float iv = sinv[ct * 32 + lr];
#pragma unroll
            for (int r = 0; r < 16; ++r) {
                int rowblk = (r & 3) + 8 * (r >> 2) + 4 * hi5 + 32 * w;
                int q = (int)fmaf(acc[ct][r], iv, 0.5f);
                T[ct * 32 + lr][rowblk] = (unsigned char)(q > 255 ? 255 : q);
            }
        }
        __syncthreads();
        {
            int r2 = t >> 1, hf = t & 1;
            size_t grow = (size_t)bz * NN + (size_t)bj * 128 + r2;
            unsigned char* dst = Ct + grow * NN + (size_t)bi * 128 + 64 * hf;
            const uint4* src = (const uint4*)&T[r2][64 * hf];
            uint4 v0 = src[0], v1 = src[1], v2 = src[2], v3 = src[3];
            *(uint4*)(dst + 0)  = v0;
            *(uint4*)(dst + 16) = v1;
            *(uint4*)(dst + 32) = v2;
            *(uint4*)(dst + 48) = v3;
        }
    }
}

// ---------- Sinkhorn iteration phase (one launch per phase; the launch
// boundary IS the grid-wide barrier — r8: cg::grid.sync ~60 us at 2k blocks).
// Grid: blocks [0, half) = lse pass (f or g); [half, 2*half) = sym pass.
// After SYMITER iterations the sym potentials are at their f32 fixed point,
// so later launches pass grid = half (lse halves only). ----
struct SArgs {
    const unsigned char *Qxy, *Qyx, *Qxx, *Qyy;   // group-relative [G][2048][2048]
    const float *Sxy, *Syx, *Sxx, *Syy;           // global [NB*NN*16]
    float *Fa, *Gt, *Px, *Py;                     // global [NB*NN]
    float *PaxA, *PaxB, *PayA, *PayB;             // global [NB*NN]
    const float *hx, *hy;                         // global [NB*NN]
    int b0;                                       // batch base of this group
};

#define BSHIFT 7

__global__ __launch_bounds__(256, 4) void k_step(SArgs a, int cur, int ph, int half) {
    __shared__ __align__(16) float vs[2048];
    int bid = blockIdx.x;
    int mh = bid >= half;
    int rem = mh ? bid - half : bid;
    int brel = rem >> BSHIFT;
    int rb = rem & ((1 << BSHIFT) - 1);
    const int rpb = NN >> BSHIFT;      // rows per block
    const int rpw = rpb >> 2;          // rows per wave
    int r0 = rb * rpb;
    int t = threadIdx.x;
    int w = t >> 6, l = t & 63;
    size_t bg = (size_t)(a.b0 + brel);
    size_t gx0 = (bg << 11) + r0 + w * rpw;                       // global row base (this wave)
    size_t qbase = ((((size_t)brel << 11) + r0 + w * rpw) << 11); // group-relative Q offset

    const unsigned char* Q;
    const float* S;
    const float* v;
    float* Pa_w = nullptr;
    const float* hp = nullptr;
    float* Pp = nullptr;
    if (ph == 0) {
        if (mh == 0) { Q = a.Qxy; S = a.Sxy; v = a.Gt + (bg << 11); }
        else { Q = a.Qxx; S = a.Sxx; v = (cur ? a.PaxB : a.PaxA) + (bg << 11);
               Pa_w = cur ? a.PaxA : a.PaxB; hp = a.hx; Pp = a.Px; }
    } else {
        if (mh == 0) { Q = a.Qyx; S = a.Syx; v = a.Fa + (bg << 11); }
        else { Q = a.Qyy; S = a.Syy; v = (cur ? a.PayB : a.PayA) + (bg << 11);
               Pa_w = cur ? a.PayA : a.PayB; hp = a.hy; Pp = a.Py; }
    }
    float* out0 = (ph == 0) ? a.Fa : a.Gt;

    // stage v into LDS with XOR swizzle (breaks 128B-stride bank conflict)
    {
        const float4* gv = (const float4*)v;
        float4 a0 = gv[2 * t], a1 = gv[2 * t + 1];
        int B0 = t << 5;
        int sw = ((t >> 2) & 7) << 4;
        *(float4*)((char*)vs + (B0 ^ sw)) = a0;
        *(float4*)((char*)vs + ((B0 + 16) ^ sw)) = a1;
    }
    __syncthreads();
    float vv[32];
#pragma unroll
    for (int u = 0; u < 8; ++u) {
        int B = ((l << 7) + (u << 4)) ^ ((l & 7) << 4);
        *(float4*)&vv[u * 4] = *(const float4*)((char*)vs + B);
    }

    const unsigned char* rp0 = Q + qbase + ((size_t)l << 5);
    uint4 qa = *(const uint4*)rp0;
    uint4 qb = *(const uint4*)(rp0 + 16);
    float sc = S[(gx0 << 4) + (l >> 2)];
#pragma unroll 1
    for (int r = 0; r < rpw; ++r) {
        uint4 na, nb2; float nsc;
        if (r < rpw - 1) {
            const unsigned char* np = rp0 + ((size_t)(r + 1) << 11);
            na = *(const uint4*)np;
            nb2 = *(const uint4*)(np + 16);
            nsc = S[((gx0 + r + 1) << 4) + (l >> 2)];
        }
        unsigned int qs[8] = {qa.x, qa.y, qa.z, qa.w, qb.x, qb.y, qb.z, qb.w};
        float m0 = -INFINITY, m1 = -INFINITY, m2 = -INFINITY, m3 = -INFINITY;
#pragma unroll
        for (int u = 0; u < 8; ++u) {
            unsigned int q = qs[u];
            m0 = fmaxf(m0, fmaf((float)(unsigned char)(q      ), sc, vv[4 * u + 0]));
            m1 = fmaxf(m1, fmaf((float)(unsigned char)(q >>  8), sc, vv[4 * u + 1]));
            m2 = fmaxf(m2, fmaf((float)(unsigned char)(q >> 16), sc, vv[4 * u + 2]));
            m3 = fmaxf(m3, fmaf((float)(q >> 24),                sc, vv[4 * u + 3]));
        }
        float mx = fmaxf(fmaxf(m0, m1), fmaxf(m2, m3));
#pragma unroll
        for (int off = 32; off; off >>= 1) mx = fmaxf(mx, __shfl_xor(mx, off));
        float s0 = 0.f, s1 = 0.f, s2 = 0.f, s3 = 0.f;
#pragma unroll
        for (int u = 0; u < 8; ++u) {
            unsigned int q = qs[u];
            s0 += __builtin_amdgcn_exp2f(fmaf((float)(unsigned char)(q      ), sc, vv[4 * u + 0]) - mx);
            s1 += __builtin_amdgcn_exp2f(fmaf((float)(unsigned char)(q >>  8), sc, vv[4 * u + 1]) - mx);
            s2 += __builtin_amdgcn_exp2f(fmaf((float)(unsigned char)(q >> 16), sc, vv[4 * u + 2]) - mx);
            s3 += __builtin_amdgcn_exp2f(fmaf((float)(q >> 24),                sc, vv[4 * u + 3]) - mx);
        }
        float ss = (s0 + s1) + (s2 + s3);
#pragma unroll
        for (int off = 32; off; off >>= 1) ss += __shfl_xor(ss, off);
        if (l == 0) {
            size_t gx = gx0 + r;
            float lse2 = mx + log2f(ss);
            if (mh == 0) {
                out0[gx] = LNEG2 - lse2;
            } else {
                float pn = 0.5f * (Pp[gx] + hp[gx] - lse2);
                Pp[gx] = pn;
                Pa_w[gx] = LNEG2 + pn - hp[gx];
            }
        }
        qa = na; qb = nb2; sc = nsc;
    }
}

// ---------- final reduction (log2 domain -> natural) ----------
__global__ __launch_bounds__(256) void k_final(const float* __restrict__ Fa, const float* __restrict__ Gt,
                                               const float* __restrict__ Px, const float* __restrict__ Py,
                                               const float* __restrict__ hx, const float* __restrict__ hy,
                                               float* __restrict__ out) {
    int t = threadIdx.x;
    double acc = 0.0;
    for (int i = t; i < NB * NN; i += 256) {
        acc += (double)(Fa[i] + hx[i]) + (double)(Gt[i] + hy[i])
             - (double)Px[i] - (double)Py[i];
    }
    __shared__ double ld[256];
    ld[t] = acc;
    __syncthreads();
    for (int off = 128; off > 0; off >>= 1) {
        if (t < off) ld[t] += ld[t + off];
        __syncthreads();
    }
    if (t == 0) {
        double total = ld[0] - 2.0 * (double)LNEG2 * (double)(NB * NN);
        out[0] = (float)((double)EPS_F * 0.6931471805599453 * total / (double)NN);
    }
}

extern "C" void kernel_launch(void* const* d_in, const int* in_sizes, int n_in,
                              void* d_out, int out_size, void* d_ws, size_t ws_size,
                              hipStream_t stream) {
    (void)in_sizes; (void)n_in; (void)out_size;
    const float* x = (const float*)d_in[0];
    const float* y = (const float*)d_in[1];
    float* out = (float*)d_out;

    char* ws = (char*)d_ws;
    size_t off = 0;
    auto alloc = [&](size_t bytes) -> char* {
        char* p = ws + off;
        off += (bytes + 255) & ~(size_t)255;
        return p;
    };

    ushort_t* X2h = (ushort_t*)alloc((size_t)NB * NN * ND * 2);
    ushort_t* X2l = (ushort_t*)alloc((size_t)NB * NN * ND * 2);
    ushort_t* Y2h = (ushort_t*)alloc((size_t)NB * NN * ND * 2);
    ushort_t* Y2l = (ushort_t*)alloc((size_t)NB * NN * ND * 2);
    float* wx = (float*)alloc(ND * 4);
    float* wy = (float*)alloc(ND * 4);
    float* hx = (float*)alloc((size_t)NB * NN * 4);
    float* hy = (float*)alloc((size_t)NB * NN * 4);
    float* Fa = (float*)alloc((size_t)NB * NN * 4);
    float* Gt = (float*)alloc((size_t)NB * NN * 4);
    float* Px = (float*)alloc((size_t)NB * NN * 4);
    float* Py = (float*)alloc((size_t)NB * NN * 4);
    float* PaxA = (float*)alloc((size_t)NB * NN * 4);
    float* PaxB = (float*)alloc((size_t)NB * NN * 4);
    float* PayA = (float*)alloc((size_t)NB * NN * 4);
    float* PayB = (float*)alloc((size_t)NB * NN * 4);
    float* Sxy = (float*)alloc((size_t)NB * NN * 16 * 4);
    float* Syx = (float*)alloc((size_t)NB * NN * 16 * 4);
    float* Sxx = (float*)alloc((size_t)NB * NN * 16 * 4);
    float* Syy = (float*)alloc((size_t)NB * NN * 16 * 4);

    // Q matrices: 4 * 4MB per batch in group; shrink group if workspace is small
    size_t small_end = off;
    size_t matBytes = (size_t)NN * NN;               // 4 MB (u8)
    int G = NB;
    while (G > 1 && small_end + 4 * matBytes * (size_t)G + 4096 > ws_size) G >>= 1;
    unsigned char* Qxy = (unsigned char*)alloc(matBytes * (size_t)G);
    unsigned char* Qyx = (unsigned char*)alloc(matBytes * (size_t)G);
    unsigned char* Qxx = (unsigned char*)alloc(matBytes * (size_t)G);
    unsigned char* Qyy = (unsigned char*)alloc(matBytes * (size_t)G);

    int halfblk = G << BSHIFT;                       // lse-half block count

    k_colsum<<<dim3(ND, 2), 256, 0, stream>>>(x, y, wx, wy);
    k_norm<<<dim3(NB * NN, 2), 128, 0, stream>>>(x, y, wx, wy, X2h, X2l, Y2h, Y2l, hx, hy);
    k_init<<<dim3(NB * NN / 256), 256, 0, stream>>>(hx, hy, Gt, Px, PaxA, Py, PayA);

    for (int b0 = 0; b0 < NB; b0 += G) {
        // xy: full grid, emits Qxy (row-scaled) + Qyx (transposed, col-scaled)
        k_gemm<true, false><<<dim3(16, 16, G), 256, 0, stream>>>(
            X2h, X2l, Y2h, Y2l, Sxy, Syx, Qxy, Qyx, b0);
        // xx/yy: symmetric -> lower-triangle grid; DO_T mirrors into upper half
        k_gemm<true, true><<<dim3(136, G), 256, 0, stream>>>(
            X2h, X2l, X2h, X2l, Sxx, Sxx, Qxx, Qxx, b0);
        k_gemm<true, true><<<dim3(136, G), 256, 0, stream>>>(
            Y2h, Y2l, Y2h, Y2l, Syy, Syy, Qyy, Qyy, b0);

        SArgs sa;
        sa.Qxy = Qxy; sa.Qyx = Qyx; sa.Qxx = Qxx; sa.Qyy = Qyy;
        sa.Sxy = Sxy; sa.Syx = Syx; sa.Sxx = Sxx; sa.Syy = Syy;
        sa.Fa = Fa; sa.Gt = Gt; sa.Px = Px; sa.Py = Py;
        sa.PaxA = PaxA; sa.PaxB = PaxB; sa.PayA = PayA; sa.PayB = PayB;
        sa.hx = hx; sa.hy = hy; sa.b0 = b0;

        int cur = 0;
        for (int it = 0; it < NITER; ++it) {
            int nblk = (it < SYMITER) ? 2 * halfblk : halfblk;
            k_step<<<dim3(nblk), 256, 0, stream>>>(sa, cur, 0, halfblk);
            k_step<<<dim3(nblk), 256, 0, stream>>>(sa, cur, 1, halfblk);
            cur ^= 1;
        }
    }
    k_final<<<dim3(1), 256, 0, stream>>>(Fa, Gt, Px, Py, hx, hy, out);
}

// Round 14
// 791.148 us; speedup vs baseline: 2.4265x; 1.3700x over previous
//
#include <hip/hip_runtime.h>
#include <math.h>

#define NB 8
#define NN 2048
#define ND 128
#define NITER 32

typedef unsigned short ushort_t;
typedef __attribute__((ext_vector_type(8))) short bf16x8;
typedef __attribute__((ext_vector_type(16))) float f32x16;

// eps = blur^2 = (5e-5)^2 = 2.5e-9. All potentials stored in LOG2-scaled units:
// F2 = (f/eps)*log2e etc. M2_ij = dot_ij/eps*log2e = q_ij * S_tile(row).
//
// SYM DEBIAS IS ANALYTIC: in f32 the sym lse is exactly its diagonal term
// (off-diag exp(-C/eps) with C/eps ~ 1e4 nats underflows to 0; log1p(0)=0),
// so the reference's p converges to -eps*loga/2 EXACTLY at iteration 1:
// px = py = log2(2048)/2 = 5.5 scaled units. No Qxx/Qyy matrices, no sym
// passes needed (r13 verified: truncating sym left absmax bit-identical).
#define EPS_F   2.5e-9f
#define LNEG2   (-11.0f)                                   /* log2(1/2048) */
#define HSCALE2 ((float)(0.5 * 1.4426950408889634 / 2.5e-9))
#define SK2     ((float)(1.4426950408889634 / (255.0 * 2.5e-9)))

// ---------- preprocessing ----------

// wx[d] = sum_t x[0,t,d]^2  (reference quirk: batch 0 only), same for y
__global__ __launch_bounds__(256) void k_colsum(const float* __restrict__ x,
                                                const float* __restrict__ y,
                                                float* __restrict__ wx,
                                                float* __restrict__ wy) {
    const float* in = blockIdx.y ? y : x;
    float* w = blockIdx.y ? wy : wx;
    int d = blockIdx.x;
    int t = threadIdx.x;
    float sum = 0.f;
    for (int k = t; k < NN; k += 256) {
        float v = in[(size_t)k * ND + d];
        sum += v * v;
    }
    for (int off = 32; off > 0; off >>= 1) sum += __shfl_down(sum, off);
    __shared__ float ls[4];
    if ((t & 63) == 0) ls[t >> 6] = sum;
    __syncthreads();
    if (t == 0) w[d] = ls[0] + ls[1] + ls[2] + ls[3];
}

// v2 = x^2/wx split into bf16 hi + bf16 lo residual; h2 = 0.5*|v2 row|^2/eps*log2e
__global__ __launch_bounds__(128) void k_norm(const float* __restrict__ x,
                                              const float* __restrict__ y,
                                              const float* __restrict__ wx,
                                              const float* __restrict__ wy,
                                              ushort_t* __restrict__ X2h,
                                              ushort_t* __restrict__ X2l,
                                              ushort_t* __restrict__ Y2h,
                                              ushort_t* __restrict__ Y2l,
                                              float* __restrict__ hx,
                                              float* __restrict__ hy) {
    int gx = blockIdx.x;                 // b*NN + i
    const float* in = blockIdx.y ? y : x;
    const float* w  = blockIdx.y ? wy : wx;
    ushort_t* oh = blockIdx.y ? Y2h : X2h;
    ushort_t* ol = blockIdx.y ? Y2l : X2l;
    float* h  = blockIdx.y ? hy : hx;
    int d = threadIdx.x;
    size_t base = (size_t)gx * ND;
    float v = in[base + d];
    float v2 = (v * v) / w[d];
    // RTNE bf16 split: v2 = hi + lo + O(2^-17 * v2)
    unsigned u = __float_as_uint(v2);
    unsigned short hs = (unsigned short)((u + 0x7fffu + ((u >> 16) & 1u)) >> 16);
    float hf = __uint_as_float((unsigned)hs << 16);
    float lo = v2 - hf;
    unsigned ul = __float_as_uint(lo);
    unsigned short lsq = (unsigned short)((ul + 0x7fffu + ((ul >> 16) & 1u)) >> 16);
    oh[base + d] = hs;
    ol[base + d] = lsq;
    float sq = v2 * v2;
    for (int off = 32; off > 0; off >>= 1) sq += __shfl_down(sq, off);
    __shared__ float ls[2];
    if ((d & 63) == 0) ls[d >> 6] = sq;
    __syncthreads();
    if (d == 0) h[gx] = (ls[0] + ls[1]) * HSCALE2;
}

__global__ __launch_bounds__(256) void k_init(const float* __restrict__ hy,
                                              float* __restrict__ Gt) {
    int tid = blockIdx.x * 256 + threadIdx.x;
    Gt[tid] = LNEG2 - hy[tid];
}

// ---------- MFMA GEMM (bf16 hi/lo split) + per-(row,128-col-tile) max u8 quant ----------
// dot = hi*hi + hi*lo + lo*hi  (lo*lo dropped: ~2^-18 relative).
// C/D layout (m74/m101): col=lane&31, row=(reg&3)+8*(reg>>2)+4*(lane>>5).
// Emits Qxy (row-scaled) and Qyx (transposed, col-scaled) in one pass.
__global__ __launch_bounds__(256, 4) void k_gemm(const ushort_t* __restrict__ Ah,
                                                 const ushort_t* __restrict__ Al,
                                                 const ushort_t* __restrict__ Bh,
                                                 const ushort_t* __restrict__ Bl,
                                                 float* __restrict__ Srow,
                                                 float* __restrict__ Scol,
                                                 unsigned char* __restrict__ C,
                                                 unsigned char* __restrict__ Ct,
                                                 int b0) {
    __shared__ __align__(16) char smem[24576];
    int bi = blockIdx.x, bj = blockIdx.y, bz = blockIdx.z;
    size_t bg = (size_t)(b0 + bz);
    int t = threadIdx.x;
    int w = t >> 6, l = t & 63;
    int lr = l & 31, hi5 = l >> 5;
    int lk = hi5 * 16;                          // frag k-offset bytes

    f32x16 acc[4];
#pragma unroll
    for (int ct = 0; ct < 4; ++ct)
#pragma unroll
        for (int i = 0; i < 16; ++i) acc[ct][i] = 0.f;

    const int srow = t >> 1;
    const int spart = (t & 1) << 4;             // 0/16 bytes
    const size_t arow0 = (bg * NN + (size_t)bi * 128 + srow) * ND;
    const size_t brow0 = (bg * NN + (size_t)bj * 128 + srow) * ND;

    for (int kt = 0; kt < 8; ++kt) {
        __syncthreads();
        {
            size_t gA = (arow0 + kt * 16 + (t & 1) * 8) * 2;
            size_t gB = (brow0 + kt * 16 + (t & 1) * 8) * 2;
            int ld = srow * 48 + spart;
            *(uint4*)(smem + ld)         = *(const uint4*)((const char*)Ah + gA);
            *(uint4*)(smem + 6144 + ld)  = *(const uint4*)((const char*)Al + gA);
            *(uint4*)(smem + 12288 + ld) = *(const uint4*)((const char*)Bh + gB);
            *(uint4*)(smem + 18432 + ld) = *(const uint4*)((const char*)Bl + gB);
        }
        __syncthreads();
        int ar = (32 * w + lr) * 48 + lk;
        bf16x8 ah = *(const bf16x8*)(smem + ar);
        bf16x8 al = *(const bf16x8*)(smem + 6144 + ar);
#pragma unroll
        for (int ct = 0; ct < 4; ++ct) {
            int br = (32 * ct + lr) * 48 + lk;
            bf16x8 bh = *(const bf16x8*)(smem + 12288 + br);
            bf16x8 bl = *(const bf16x8*)(smem + 18432 + br);
            acc[ct] = __builtin_amdgcn_mfma_f32_32x32x16_bf16(ah, bh, acc[ct], 0, 0, 0);
            acc[ct] = __builtin_amdgcn_mfma_f32_32x32x16_bf16(ah, bl, acc[ct], 0, 0, 0);
            acc[ct] = __builtin_amdgcn_mfma_f32_32x32x16_bf16(al, bh, acc[ct], 0, 0, 0);
        }
    }

    // ---- row maxes (over the block's 128 cols) + scales ----
    float inv_r[16];
#pragma unroll
    for (int r = 0; r < 16; ++r) {
        float m0 = fmaxf(fmaxf(acc[0][r], acc[1][r]), fmaxf(acc[2][r], acc[3][r]));
#pragma unroll
        for (int off = 1; off <= 16; off <<= 1) m0 = fmaxf(m0, __shfl_xor(m0, off));
        m0 = fmaxf(m0, 1e-30f);
        inv_r[r] = 255.f / m0;
        if (lr == 0) {
            int rowblk = (r & 3) + 8 * (r >> 2) + 4 * hi5 + 32 * w;
            Srow[(bg * NN + (size_t)bi * 128 + rowblk) * 16 + bj] = m0 * SK2;
        }
    }
    __syncthreads();            // staging dead; T aliases smem
    unsigned char (*T)[144] = (unsigned char (*)[144])smem;
#pragma unroll
    for (int ct = 0; ct < 4; ++ct)
#pragma unroll
        for (int r = 0; r < 16; ++r) {
            int rowblk = (r & 3) + 8 * (r >> 2) + 4 * hi5 + 32 * w;
            int q = (int)fmaf(acc[ct][r], inv_r[r], 0.5f);
            T[rowblk][ct * 32 + lr] = (unsigned char)(q > 255 ? 255 : q);
        }
    __syncthreads();
    {
        int r2 = t >> 1, hf = t & 1;
        size_t grow = (size_t)bz * NN + (size_t)bi * 128 + r2;
        unsigned char* dst = C + grow * NN + (size_t)bj * 128 + 64 * hf;
        const uint4* src = (const uint4*)&T[r2][64 * hf];
        uint4 v0 = src[0], v1 = src[1], v2 = src[2], v3 = src[3];
        *(uint4*)(dst + 0)  = v0;
        *(uint4*)(dst + 16) = v1;
        *(uint4*)(dst + 32) = v2;
        *(uint4*)(dst + 48) = v3;
    }
    // ---- transposed, column-scaled pass ----
    {
        float* sinv = (float*)(smem + 18432);
        float* CMf  = (float*)(smem + 18944);   // [4][128]
        __syncthreads();                        // pass-1 T reads done
#pragma unroll
        for (int ct = 0; ct < 4; ++ct) {
            float cm = acc[ct][0];
#pragma unroll
            for (int r = 1; r < 16; ++r) cm = fmaxf(cm, acc[ct][r]);
            cm = fmaxf(cm, __shfl_xor(cm, 32));
            if (hi5 == 0) CMf[w * 128 + ct * 32 + lr] = cm;
        }
        __syncthreads();
        if (t < 128) {
            float cm = fmaxf(fmaxf(CMf[t], CMf[128 + t]), fmaxf(CMf[256 + t], CMf[384 + t]));
            cm = fmaxf(cm, 1e-30f);
            Scol[(bg * NN + (size_t)bj * 128 + t) * 16 + bi] = cm * SK2;
            sinv[t] = 255.f / cm;
        }
        __syncthreads();
#pragma unroll
        for (int ct = 0; ct < 4; ++ct) {
            float iv = sinv[ct * 32 + lr];
#pragma unroll
            for (int r = 0; r < 16; ++r) {
                int rowblk = (r & 3) + 8 * (r >> 2) + 4 * hi5 + 32 * w;
                int q = (int)fmaf(acc[ct][r], iv, 0.5f);
                T[ct * 32 + lr][rowblk] = (unsigned char)(q > 255 ? 255 : q);
            }
        }
        __syncthreads();
        {
            int r2 = t >> 1, hf = t & 1;
            size_t grow = (size_t)bz * NN + (size_t)bj * 128 + r2;
            unsigned char* dst = Ct + grow * NN + (size_t)bi * 128 + 64 * hf;
            const uint4* src = (const uint4*)&T[r2][64 * hf];
            uint4 v0 = src[0], v1 = src[1], v2 = src[2], v3 = src[3];
            *(uint4*)(dst + 0)  = v0;
            *(uint4*)(dst + 16) = v1;
            *(uint4*)(dst + 32) = v2;
            *(uint4*)(dst + 48) = v3;
        }
    }
}

// ---------- Sinkhorn f/g phase (one launch per phase; launch boundary =
// grid barrier — r8: cg::grid.sync ~60 us at 2k blocks vs ~4 us launch) ----
struct SArgs {
    const unsigned char *Qxy, *Qyx;               // group-relative [G][2048][2048]
    const float *Sxy, *Syx;                       // global [NB*NN*16]
    float *Fa, *Gt;                               // global [NB*NN]
    int b0;                                       // batch base of this group
};

#define BSHIFT 7

__global__ __launch_bounds__(256, 4) void k_step(SArgs a, int ph) {
    __shared__ __align__(16) float vs[2048];
    int bid = blockIdx.x;
    int brel = bid >> BSHIFT;
    int rb = bid & ((1 << BSHIFT) - 1);
    const int rpb = NN >> BSHIFT;      // rows per block
    const int rpw = rpb >> 2;          // rows per wave
    int r0 = rb * rpb;
    int t = threadIdx.x;
    int w = t >> 6, l = t & 63;
    size_t bg = (size_t)(a.b0 + brel);
    size_t gx0 = (bg << 11) + r0 + w * rpw;                       // global row base (this wave)
    size_t qbase = ((((size_t)brel << 11) + r0 + w * rpw) << 11); // group-relative Q offset

    const unsigned char* Q = ph ? a.Qyx : a.Qxy;
    const float* S         = ph ? a.Syx : a.Sxy;
    const float* v         = (ph ? a.Fa : a.Gt) + (bg << 11);
    float* out0            = ph ? a.Gt : a.Fa;

    // stage v into LDS with XOR swizzle (breaks 128B-stride bank conflict)
    {
        const float4* gv = (const float4*)v;
        float4 a0 = gv[2 * t], a1 = gv[2 * t + 1];
        int B0 = t << 5;
        int sw = ((t >> 2) & 7) << 4;
        *(float4*)((char*)vs + (B0 ^ sw)) = a0;
        *(float4*)((char*)vs + ((B0 + 16) ^ sw)) = a1;
    }
    __syncthreads();
    float vv[32];
#pragma unroll
    for (int u = 0; u < 8; ++u) {
        int B = ((l << 7) + (u << 4)) ^ ((l & 7) << 4);
        *(float4*)&vv[u * 4] = *(const float4*)((char*)vs + B);
    }

    const unsigned char* rp0 = Q + qbase + ((size_t)l << 5);
    uint4 qa = *(const uint4*)rp0;
    uint4 qb = *(const uint4*)(rp0 + 16);
    float sc = S[(gx0 << 4) + (l >> 2)];
#pragma unroll 1
    for (int r = 0; r < rpw; ++r) {
        uint4 na, nb2; float nsc;
        if (r < rpw - 1) {
            const unsigned char* np = rp0 + ((size_t)(r + 1) << 11);
            na = *(const uint4*)np;
            nb2 = *(const uint4*)(np + 16);
            nsc = S[((gx0 + r + 1) << 4) + (l >> 2)];
        }
        unsigned int qs[8] = {qa.x, qa.y, qa.z, qa.w, qb.x, qb.y, qb.z, qb.w};
        float m0 = -INFINITY, m1 = -INFINITY, m2 = -INFINITY, m3 = -INFINITY;
#pragma unroll
        for (int u = 0; u < 8; ++u) {
            unsigned int q = qs[u];
            m0 = fmaxf(m0, fmaf((float)(unsigned char)(q      ), sc, vv[4 * u + 0]));
            m1 = fmaxf(m1, fmaf((float)(unsigned char)(q >>  8), sc, vv[4 * u + 1]));
            m2 = fmaxf(m2, fmaf((float)(unsigned char)(q >> 16), sc, vv[4 * u + 2]));
            m3 = fmaxf(m3, fmaf((float)(q >> 24),                sc, vv[4 * u + 3]));
        }
        float mx = fmaxf(fmaxf(m0, m1), fmaxf(m2, m3));
#pragma unroll
        for (int off = 32; off; off >>= 1) mx = fmaxf(mx, __shfl_xor(mx, off));
        float s0 = 0.f, s1 = 0.f, s2 = 0.f, s3 = 0.f;
#pragma unroll
        for (int u = 0; u < 8; ++u) {
            unsigned int q = qs[u];
            s0 += __builtin_amdgcn_exp2f(fmaf((float)(unsigned char)(q      ), sc, vv[4 * u + 0]) - mx);
            s1 += __builtin_amdgcn_exp2f(fmaf((float)(unsigned char)(q >>  8), sc, vv[4 * u + 1]) - mx);
            s2 += __builtin_amdgcn_exp2f(fmaf((float)(unsigned char)(q >> 16), sc, vv[4 * u + 2]) - mx);
            s3 += __builtin_amdgcn_exp2f(fmaf((float)(q >> 24),                sc, vv[4 * u + 3]) - mx);
        }
        float ss = (s0 + s1) + (s2 + s3);
#pragma unroll
        for (int off = 32; off; off >>= 1) ss += __shfl_xor(ss, off);
        if (l == 0) {
            out0[gx0 + r] = LNEG2 - (mx + log2f(ss));
        }
        qa = na; qb = nb2; sc = nsc;
    }
}

// ---------- final reduction (log2 domain -> natural) ----------
// px = py = 5.5 exactly (analytic sym fixed point) -> -px-py = -11 per elem.
__global__ __launch_bounds__(256) void k_final(const float* __restrict__ Fa, const float* __restrict__ Gt,
                                               const float* __restrict__ hx, const float* __restrict__ hy,
                                               float* __restrict__ out) {
    int t = threadIdx.x;
    double acc = 0.0;
    for (int i = t; i < NB * NN; i += 256) {
        acc += (double)(Fa[i] + hx[i]) + (double)(Gt[i] + hy[i]) - 11.0;
    }
    __shared__ double ld[256];
    ld[t] = acc;
    __syncthreads();
    for (int off = 128; off > 0; off >>= 1) {
        if (t < off) ld[t] += ld[t + off];
        __syncthreads();
    }
    if (t == 0) {
        double total = ld[0] - 2.0 * (double)LNEG2 * (double)(NB * NN);
        out[0] = (float)((double)EPS_F * 0.6931471805599453 * total / (double)NN);
    }
}

extern "C" void kernel_launch(void* const* d_in, const int* in_sizes, int n_in,
                              void* d_out, int out_size, void* d_ws, size_t ws_size,
                              hipStream_t stream) {
    (void)in_sizes; (void)n_in; (void)out_size;
    const float* x = (const float*)d_in[0];
    const float* y = (const float*)d_in[1];
    float* out = (float*)d_out;

    char* ws = (char*)d_ws;
    size_t off = 0;
    auto alloc = [&](size_t bytes) -> char* {
        char* p = ws + off;
        off += (bytes + 255) & ~(size_t)255;
        return p;
    };

    ushort_t* X2h = (ushort_t*)alloc((size_t)NB * NN * ND * 2);
    ushort_t* X2l = (ushort_t*)alloc((size_t)NB * NN * ND * 2);
    ushort_t* Y2h = (ushort_t*)alloc((size_t)NB * NN * ND * 2);
    ushort_t* Y2l = (ushort_t*)alloc((size_t)NB * NN * ND * 2);
    float* wx = (float*)alloc(ND * 4);
    float* wy = (float*)alloc(ND * 4);
    float* hx = (float*)alloc((size_t)NB * NN * 4);
    float* hy = (float*)alloc((size_t)NB * NN * 4);
    float* Fa = (float*)alloc((size_t)NB * NN * 4);
    float* Gt = (float*)alloc((size_t)NB * NN * 4);
    float* Sxy = (float*)alloc((size_t)NB * NN * 16 * 4);
    float* Syx = (float*)alloc((size_t)NB * NN * 16 * 4);

    // Q matrices: 2 * 4MB per batch in group; shrink group if workspace is small
    size_t small_end = off;
    size_t matBytes = (size_t)NN * NN;               // 4 MB (u8)
    int G = NB;
    while (G > 1 && small_end + 2 * matBytes * (size_t)G + 4096 > ws_size) G >>= 1;
    unsigned char* Qxy = (unsigned char*)alloc(matBytes * (size_t)G);
    unsigned char* Qyx = (unsigned char*)alloc(matBytes * (size_t)G);

    int nblk = G << BSHIFT;                          // 1024 blocks at G=8

    k_colsum<<<dim3(ND, 2), 256, 0, stream>>>(x, y, wx, wy);
    k_norm<<<dim3(NB * NN, 2), 128, 0, stream>>>(x, y, wx, wy, X2h, X2l, Y2h, Y2l, hx, hy);
    k_init<<<dim3(NB * NN / 256), 256, 0, stream>>>(hy, Gt);

    for (int b0 = 0; b0 < NB; b0 += G) {
        k_gemm<<<dim3(16, 16, G), 256, 0, stream>>>(
            X2h, X2l, Y2h, Y2l, Sxy, Syx, Qxy, Qyx, b0);

        SArgs sa;
        sa.Qxy = Qxy; sa.Qyx = Qyx;
        sa.Sxy = Sxy; sa.Syx = Syx;
        sa.Fa = Fa; sa.Gt = Gt;
        sa.b0 = b0;

        for (int it = 0; it < NITER; ++it) {
            k_step<<<dim3(nblk), 256, 0, stream>>>(sa, 0);
            k_step<<<dim3(nblk), 256, 0, stream>>>(sa, 1);
        }
    }
    k_final<<<dim3(1), 256, 0, stream>>>(Fa, Gt, hx, hy, out);
}